// Round 15
// baseline (133.712 us; speedup 1.0000x reference)
//
#include <hip/hip_runtime.h>
#include <cstddef>

#define B 8
constexpr int TAIL_NB = 256;  // tail kernel grid (<= 256 CUs: co-resident, gbar-safe)

constexpr float DM = 0.95122942450071400910f; // exp(-1/20) in f32
constexpr float DS = 0.81873075307798185867f; // exp(-1/5) in f32

// bucket strides (elements per (t,b) bucket) = neurons per batch
constexpr int BS_L0 = 3 * 32 * 32;    // 3072
constexpr int BS_L1 = 64 * 32 * 32;   // 65536
constexpr int BS_P1 = 128 * 16 * 16;  // 32768
constexpr int BS_P2 = 256 * 8 * 8;    // 16384
constexpr int BS_L4 = 512 * 8 * 8;    // 32768
constexpr int BS_L5 = 256 * 8 * 8;    // 16384
constexpr int BS_F1 = 1024;
constexpr int BS_F2 = 512;

// ---- int workspace layout ----
constexpr size_t I_L0 = 0;
constexpr size_t I_L1 = I_L0 + 8 * (size_t)B * BS_L0;
constexpr size_t I_P1 = I_L1 + 8 * (size_t)B * BS_L1;
constexpr size_t I_P2 = I_P1 + 8 * (size_t)B * BS_P1;
constexpr size_t I_L4 = I_P2 + 8 * (size_t)B * BS_P2;
constexpr size_t I_L5 = I_L4 + 8 * (size_t)B * BS_L4;
constexpr size_t I_F1 = I_L5 + 8 * (size_t)B * BS_L5;
constexpr size_t I_F2 = I_F1 + 8 * (size_t)B * BS_F1;
constexpr size_t I_CNT = I_F2 + 8 * (size_t)B * BS_F2;  // 512 counters: [(t*8+ci)*8+b]
constexpr size_t I_SUMP = I_CNT + 512;                  // 16 floats: unpooled-count partials
constexpr size_t I_BAR = I_SUMP + 16;                   // 2 barrier words
constexpr size_t INT_TOTAL = I_BAR + 2;
constexpr size_t WS_NEED = INT_TOTAL * sizeof(int);  // ~43 MB

constexpr int ilog2(int n) { int l = 0; while (n > 1) { n >>= 1; ++l; } return l; }

__device__ __forceinline__ int ldcnt(const int* p) {
  return __hip_atomic_load(p, __ATOMIC_RELAXED, __HIP_MEMORY_SCOPE_AGENT);
}

__device__ __forceinline__ void block_stage(bool sp, int idx, int* s_list, int* s_n) {
  unsigned long long bal = __ballot(sp);
  if (bal == 0ull) return;
  int lane = threadIdx.x & 63;
  int leader = (int)__ffsll((unsigned long long)bal) - 1;
  int base = 0;
  if (lane == leader) base = atomicAdd(s_n, __popcll(bal));
  base = __shfl(base, leader);
  if (sp) s_list[base + __popcll(bal & ((1ull << lane) - 1ull))] = idx;
}

__device__ __forceinline__ void wave_append(bool sp, int idx, int* cnt, int* list) {
  unsigned long long bal = __ballot(sp);
  if (bal == 0ull) return;
  int lane = threadIdx.x & 63;
  int leader = (int)__ffsll((unsigned long long)bal) - 1;
  int base = 0;
  if (lane == leader) base = atomicAdd(cnt, __popcll(bal));
  base = __shfl(base, leader);
  if (sp) list[base + __popcll(bal & ((1ull << lane) - 1ull))] = idx;
}

// single-layer gate refresh (used only after a phase actually ran)
__device__ __forceinline__ bool layer_any(const int* cnt, int ci, int tid, int* s_gate) {
  __syncthreads();
  if (tid == 0) *s_gate = 0;
  __syncthreads();
  if (tid < 64) {
    int t = tid >> 3, b = tid & 7;
    if (ldcnt(cnt + (t * 8 + ci) * 8 + b) > 0) *s_gate = 1;
  }
  __syncthreads();
  return *s_gate != 0;
}

// combined gate round: all 512 counters -> per-layer any flags (one barrier pair)
__device__ __forceinline__ void all_gates(const int* cnt, int tid, int* s_any) {
  if (tid < 8) s_any[tid] = 0;
  __syncthreads();
  for (int i = tid; i < 512; i += 256)
    if (ldcnt(cnt + i) > 0) atomicOr(&s_any[(i >> 3) & 7], 1);
  __syncthreads();
}

// generation barrier across TAIL_NB blocks (taken only on active path)
__device__ __forceinline__ void gbar(int* bar, int tid) {
  __threadfence();
  __syncthreads();
  if (tid == 0) {
    int g = __hip_atomic_load(bar + 1, __ATOMIC_RELAXED, __HIP_MEMORY_SCOPE_AGENT);
    int a = __hip_atomic_fetch_add(bar, 1, __ATOMIC_ACQ_REL, __HIP_MEMORY_SCOPE_AGENT);
    if (a == TAIL_NB - 1) {
      __hip_atomic_store(bar, 0, __ATOMIC_RELAXED, __HIP_MEMORY_SCOPE_AGENT);
      __hip_atomic_store(bar + 1, g + 1, __ATOMIC_RELEASE, __HIP_MEMORY_SCOPE_AGENT);
    } else {
      while (__hip_atomic_load(bar + 1, __ATOMIC_ACQUIRE, __HIP_MEMORY_SCOPE_AGENT) == g)
        __builtin_amdgcn_s_sleep(1);
    }
  }
  __syncthreads();
  __threadfence();
}

// encode + init, 8 blocks (one per batch) x 512 threads, TWO barriers total.
__global__ __launch_bounds__(512) void k_encode(const float* __restrict__ in,
                                                int* __restrict__ iws) {
  const int tid = threadIdx.x;
  const int b = blockIdx.x;
  int* cnt = iws + I_CNT;
  if (tid < 56) {  // zero cnt[(t,ci>=1,b)]
    int t = tid / 7, ci = 1 + tid % 7;
    cnt[(t * 8 + ci) * 8 + b] = 0;
  }
  if (b == 0 && tid >= 64 && tid < 82) iws[I_SUMP + (tid - 64)] = 0;  // sump + bar
  __shared__ unsigned long long s_bal[8 * 48];
  __shared__ int s_off[8 * 48];
  const int lane = tid & 63, w = tid >> 6;
  float x[6], u[6];
#pragma unroll
  for (int k = 0; k < 6; ++k) {
    x[k] = in[b * BS_L0 + tid + k * 512] * 0.2f;
    u[k] = 0.0f;
  }
  unsigned long long spmall = 0ull;  // bit t*6+k
#pragma clang loop unroll(disable)
  for (int t = 0; t < 8; ++t) {
#pragma unroll
    for (int k = 0; k < 6; ++k) {
      u[k] = DM * u[k] + x[k];
      bool sp = (u[k] - 1.0f > 0.0f);
      if (sp) { u[k] = 0.0f; spmall |= 1ull << (t * 6 + k); }
      unsigned long long bal = __ballot(sp);
      if (lane == 0) s_bal[t * 48 + k * 8 + w] = bal;
    }
  }
  __syncthreads();
  // wave w scans step t=w's 48 ballot popcounts (8 waves in parallel)
  if (lane < 48) {
    const int t = w;
    int v = __popcll(s_bal[t * 48 + lane]);
    int incl = v;
#pragma unroll
    for (int d = 1; d < 64; d <<= 1) {
      int o = __shfl_up(incl, d);
      if (lane >= d) incl += o;
    }
    s_off[t * 48 + lane] = incl - v;
    if (lane == 47) cnt[(t * 8 + 0) * 8 + b] = incl;  // layer-0 count (sole writer)
  }
  __syncthreads();
#pragma clang loop unroll(disable)
  for (int t = 0; t < 8; ++t) {
    int* list = iws + I_L0 + ((size_t)t * B + b) * BS_L0;
#pragma unroll
    for (int k = 0; k < 6; ++k) {
      if (spmall & (1ull << (t * 6 + k))) {
        int word = k * 8 + w;
        int rank = __popcll(s_bal[t * 48 + word] & ((1ull << lane) - 1ull));
        list[s_off[t * 48 + word] + rank] = tid + k * 512;
      }
    }
  }
}

// conv1 as tail phase 0: 2 (b,oc) planes per block, single-pass 8-plane LDS acc
// (s_big as [t][pixel]). Dead steps are exactly 0-preserving: no gating needed.
__device__ void conv1_phase(int bid, int tid, const float* __restrict__ w, int* cnt,
                            int* __restrict__ iws, float* s_big, float* s_w1, int* s_cnt) {
#pragma clang loop unroll(disable)
  for (int pl = 0; pl < 2; ++pl) {
    const int plane = bid * 2 + pl;
    const int b = plane >> 6;
    const int oc = plane & 63;
    if (tid < 8) s_cnt[tid] = ldcnt(cnt + (tid * 8 + 0) * 8 + b);
    if (tid >= 64 && tid < 139) s_w1[tid - 64] = w[oc * 75 + (tid - 64)];
#pragma clang loop unroll(disable)
    for (int i = tid; i < 8192; i += 256) s_big[i] = 0.0f;
    __syncthreads();
    // scatter all steps (no inter-step barriers: disjoint t-planes, independent atomics)
#pragma clang loop unroll(disable)
    for (int t = 0; t < 8; ++t) {
      const int S = s_cnt[t];
      if (S == 0) continue;
      const int* glist = iws + I_L0 + ((size_t)t * B + b) * BS_L0;
      const int total = S << 5;  // flattened (spike, patch-elem)
#pragma clang loop unroll(disable)
      for (int i = tid; i < total; i += 256) {
        int k = i & 31;
        if (k < 25) {
          int loc = glist[i >> 5];
          int c = loc >> 10;
          int p = loc & 1023;
          int ki = (k * 205) >> 10;  // k/5 exact for k<25
          int oy = (p >> 5) + 2 - ki;
          int ox = (p & 31) + 2 - (k - ki * 5);
          if ((unsigned)oy < 32u && (unsigned)ox < 32u)
            atomicAdd(&s_big[t * 1024 + (oy << 5) + ox], s_w1[c * 25 + k]);
        }
      }
    }
    __syncthreads();
    // 8-step recurrence, 4 px/thread, registers only
    float um[4], us4[4], sav[4];
#pragma unroll
    for (int k = 0; k < 4; ++k) { um[k] = 0.0f; us4[k] = 0.0f; sav[k] = 1.0f; }
#pragma clang loop unroll(disable)
    for (int t = 0; t < 8; ++t) {
      int* out_cnt = cnt + (t * 8 + 1) * 8 + b;
      int* out_list = iws + I_L1 + ((size_t)t * B + b) * BS_L1;
#pragma unroll
      for (int k = 0; k < 4; ++k) {
        int p = tid + (k << 8);
        float cv = s_big[t * 1024 + p];
        float m = DM * um[k] + cv;
        float s2 = DS * us4[k] + cv;
        um[k] = m;
        us4[k] = s2;
        float uu = sav[k] * (m - s2);
        bool sp = (uu - 1.0f > 0.0f);
        if (sp) sav[k] = 0.0f;
        wave_append(sp, (oc << 10) + p, out_cnt, out_list);
      }
    }
    __syncthreads();
  }
}

// conv layer phase (tail), unchanged body
template <int CIN, int COUT, int H, int W, bool POOL, int PPB, bool WLDS>
__device__ void conv_phase(int bid, int tid, const float* __restrict__ w, int* cnt, int in_ci,
                           int out_ci, const int* __restrict__ in_list0, int in_bs,
                           int* __restrict__ out_list0, int out_bs, float* sump_layer,
                           float* s_acc, float* s_plb, float* s_spb, float* s_w, int* s_list,
                           int* s_n, int* s_base, int* s_uc, int* s_cnt) {
  constexpr int HW = H * W;
  constexpr int HWlog = ilog2(HW);
  constexpr int Wlog = ilog2(W);
  constexpr int PPT = (HW + 255) / 256;
  int wcount = 0;
  const int b = (bid * PPB) >> ilog2(COUT);  // same batch for all planes in this block
  if (tid < 8) s_cnt[tid] = ldcnt(cnt + (tid * 8 + in_ci) * 8 + b);
  __syncthreads();
#pragma clang loop unroll(disable)
  for (int pl = 0; pl < PPB; ++pl) {
    const int plane = bid * PPB + pl;
    const int oc = plane & (COUT - 1);
    if constexpr (WLDS) {
#pragma clang loop unroll(disable)
      for (int j = tid; j < CIN * 25; j += 256) s_w[j] = w[(size_t)oc * CIN * 25 + j];
    }
    float um[PPT], us[PPT], sav[PPT], pe[PPT], plat[PPT];
#pragma unroll
    for (int k = 0; k < PPT; ++k) {
      um[k] = 0.0f; us[k] = 0.0f; sav[k] = 1.0f; pe[k] = 0.0f; plat[k] = 8.0f;
    }
    bool active = false;
#pragma clang loop unroll(disable)
    for (int t = 0; t < 8; ++t) {
      const int S = s_cnt[t];
      if (!active && S == 0) continue;
      active = true;
#pragma clang loop unroll(disable)
      for (int p = tid; p < HW; p += 256) s_acc[p] = 0.0f;
      if (tid == 0) *s_n = 0;
      __syncthreads();
      const int* list = in_list0 + ((size_t)t * B + b) * in_bs;
#pragma clang loop unroll(disable)
      for (int s = tid; s < S; s += 256) {
        int loc = list[s];
        int c = loc >> HWlog;
        int p = loc & (HW - 1);
        int y = p >> Wlog, x = p & (W - 1);
        const float* wp = WLDS ? (const float*)s_w + c * 25 : w + ((size_t)oc * CIN + c) * 25;
#pragma clang loop unroll(disable)
        for (int ki = 0; ki < 5; ++ki) {
          int oy = y + 2 - ki;
          if ((unsigned)oy < (unsigned)H) {
#pragma clang loop unroll(disable)
            for (int kj = 0; kj < 5; ++kj) {
              int ox = x + 2 - kj;
              if ((unsigned)ox < (unsigned)W) atomicAdd(&s_acc[oy * W + ox], wp[ki * 5 + kj]);
            }
          }
        }
      }
      __syncthreads();
#pragma unroll
      for (int k = 0; k < PPT; ++k) {
        int p = tid + k * 256;
        bool lane_ok = (p < HW);
        float cv = lane_ok ? s_acc[p] : 0.0f;
        float m = DM * um[k] + cv;
        float s2 = DS * us[k] + cv;
        um[k] = m;
        us[k] = s2;
        float uu = sav[k] * (m - s2);
        bool sp = lane_ok && (uu - 1.0f > 0.0f);
        if (sp) sav[k] = 0.0f;
        if constexpr (POOL) {
          unsigned long long bal = __ballot(sp);
          if ((tid & 63) == 0) wcount += (int)__popcll(bal);
          if (lane_ok) {
            float act = (m != 0.0f) ? 1.0f : 0.0f;
            float pen = pe[k] + (((pe[k] + act) != 0.0f) ? 1.0f : 0.0f);
            pe[k] = pen;
            if (sp) plat[k] += pen - 7.0f;
            s_plb[p] = plat[k];
            s_spb[p] = sp ? 1.0f : 0.0f;
          }
        } else {
          block_stage(sp, (oc << HWlog) + p, s_list, s_n);
        }
      }
      __syncthreads();
      if constexpr (POOL) {
        constexpr int HP = H / 2, WP = W / 2;
#pragma clang loop unroll(disable)
        for (int q = tid; q < HP * WP; q += 256) {
          int py = q / WP, px = q - py * WP;
          int base = (2 * py) * W + 2 * px;
          float l0 = s_plb[base], l1 = s_plb[base + 1], l2 = s_plb[base + W],
                l3 = s_plb[base + W + 1];
          int off = 0;
          float lm = l0;
          if (l1 < lm) { lm = l1; off = 1; }
          if (l2 < lm) { lm = l2; off = W; }
          if (l3 < lm) { lm = l3; off = W + 1; }
          bool psp = (s_spb[base + off] != 0.0f);
          block_stage(psp, oc * (HP * WP) + q, s_list, s_n);
        }
        __syncthreads();
      }
      if (tid == 0 && *s_n > 0) *s_base = atomicAdd(cnt + (t * 8 + out_ci) * 8 + b, *s_n);
      __syncthreads();
      int* out_list = out_list0 + ((size_t)t * B + b) * out_bs;
      int n = *s_n;
#pragma clang loop unroll(disable)
      for (int j = tid; j < n; j += 256) out_list[*s_base + j] = s_list[j];
      __syncthreads();
    }
  }
  if constexpr (POOL) {
    if (tid == 0) *s_uc = 0;
    __syncthreads();
    if ((tid & 63) == 0 && wcount) atomicAdd(s_uc, wcount);
    __syncthreads();
    if (tid == 0 && *s_uc) atomicAdd(sump_layer + b, (float)*s_uc);
  }
}

// fc layer phase (tail)
template <int IN, int OUT>
__device__ void fc_phase(int bid, int tid, const float* __restrict__ w, int* cnt, int in_ci,
                         int out_ci, const int* __restrict__ in_list0, int in_bs,
                         int* __restrict__ out_list0, int out_bs, int* s_list, int* s_n,
                         int* s_base, int* s_cnt) {
  const int q = bid * 256 + tid;
  const int b = q >> ilog2(OUT);
  const int o = q & (OUT - 1);
  if (tid < 8) s_cnt[tid] = ldcnt(cnt + (tid * 8 + in_ci) * 8 + b);
  __syncthreads();
  float um = 0.0f, us = 0.0f, sav = 1.0f;
  bool active = false;
#pragma clang loop unroll(disable)
  for (int t = 0; t < 8; ++t) {
    const int S = s_cnt[t];
    if (!active && S == 0) continue;
    active = true;
    if (tid == 0) *s_n = 0;
    __syncthreads();
    const int* list = in_list0 + ((size_t)t * B + b) * in_bs;
    float acc = 0.0f;
#pragma clang loop unroll(disable)
    for (int s = 0; s < S; ++s) acc += w[(size_t)o * IN + list[s]];
    float m = DM * um + acc;
    float s2 = DS * us + acc;
    um = m;
    us = s2;
    float uu = sav * (m - s2);
    bool sp = (uu - 1.0f > 0.0f);
    if (sp) sav = 0.0f;
    block_stage(sp, o, s_list, s_n);
    __syncthreads();
    if (tid == 0 && *s_n > 0) *s_base = atomicAdd(cnt + (t * 8 + out_ci) * 8 + b, *s_n);
    __syncthreads();
    int* out_list = out_list0 + ((size_t)t * B + b) * out_bs;
    int n = *s_n;
#pragma clang loop unroll(disable)
    for (int j = tid; j < n; j += 256) out_list[*s_base + j] = s_list[j];
    __syncthreads();
  }
}

// final FC (512->10) + te/out_t/out_u epilogue + sum_sp reduction (block 0)
__device__ void fc3_phase(int tid, const float* __restrict__ w, const int* cnt, int in_ci,
                          const int* __restrict__ in_list0, int in_bs,
                          const float* __restrict__ sump, float* __restrict__ out, int* s_c3) {
  if (tid == 0) *s_c3 = 0;
  __syncthreads();
  const bool lane_ok = (tid < 80);
  const int b = lane_ok ? tid / 10 : 0;
  const int o = lane_ok ? tid - b * 10 : 0;
  float um = 0.0f, us = 0.0f, sav = 1.0f, te = 0.0f, ot = 8.0f, ou = 0.0f;
  bool active = false;
#pragma clang loop unroll(disable)
  for (int t = 0; t < 8; ++t) {
    const int S = lane_ok ? ldcnt(cnt + (t * 8 + in_ci) * 8 + b) : 0;
    if (!active && !__any(S > 0)) continue;
    active = true;
    const int* list = in_list0 + ((size_t)t * B + b) * in_bs;
    float acc = 0.0f;
#pragma clang loop unroll(disable)
    for (int s = 0; s < S; ++s) acc += w[o * 512 + list[s]];
    float m = DM * um + acc;
    float s2 = DS * us + acc;
    um = m;
    us = s2;
    float uu = sav * (m - s2);
    bool sp = lane_ok && (uu - 1.0f > 0.0f);
    if (sp) sav = 0.0f;
    float act = (uu != 0.0f) ? 1.0f : 0.0f;
    te = te + (((te + act) != 0.0f) ? 1.0f : 0.0f);
    if (sp) {
      ot += te - 8.0f;
      ou += uu;
    }
    unsigned long long bal = __ballot(sp);
    if ((tid & 63) == 0 && bal) atomicAdd(s_c3, (int)__popcll(bal));
  }
  if (tid < 80) {
    out[tid] = ot;
    out[80 + tid] = ou;
  }
  __syncthreads();
  if (tid < 8) {
    float s = 0.0f;
    if (tid == 2 || tid == 3) {
      const float* sp = sump + (tid - 2) * 8;
      for (int b2 = 0; b2 < 8; ++b2) s += sp[b2];
    } else {
      for (int t = 0; t < 8; ++t)
        for (int b2 = 0; b2 < 8; ++b2) s += (float)cnt[(t * 8 + tid) * 8 + b2];
    }
    out[160 + tid] = s;
  }
  if (tid == 0) out[168] = (float)*s_c3;
}

// ONE tail dispatch: conv1..fc2 gated phases + fc3 epilogue.
// Gates: one combined 512-counter round up front; per-layer refresh ONLY after a
// phase actually ran (then counters changed; all blocks passed the gbar). If a
// phase was skipped its output counters are untouched -> upfront flag stays valid.
__global__ __launch_bounds__(256) void k_tail(const float* __restrict__ wc1,
                                              const float* __restrict__ wc2,
                                              const float* __restrict__ wc3,
                                              const float* __restrict__ wc4,
                                              const float* __restrict__ wc5,
                                              const float* __restrict__ wf1,
                                              const float* __restrict__ wf2,
                                              const float* __restrict__ wf3,
                                              float* __restrict__ out, int* __restrict__ iws) {
  __shared__ float s_big[8192];  // conv1 8-plane acc (32KB) / conv2-5 weight slice (3200)
  __shared__ float s_acc[1024];
  __shared__ float s_plb[1024];
  __shared__ float s_spb[1024];
  __shared__ int s_list[1024];
  __shared__ float s_w1[75];
  __shared__ int s_n, s_base, s_uc, s_gate, s_c3, s_cnt[8], s_any[8];
  const int tid = threadIdx.x;
  const int bid = blockIdx.x;
  int* cnt = iws + I_CNT;
  float* sump = (float*)(iws + I_SUMP);
  int* bar = iws + I_BAR;

  all_gates(cnt, tid, s_any);
  bool g0 = s_any[0] != 0, g1 = s_any[1] != 0, g2 = s_any[2] != 0, g3 = s_any[3] != 0;
  bool g4 = s_any[4] != 0, g5 = s_any[5] != 0, g6 = s_any[6] != 0;

  if (g0) {
    conv1_phase(bid, tid, wc1, cnt, iws, s_big, s_w1, s_cnt);
    gbar(bar, tid);
    g1 = layer_any(cnt, 1, tid, &s_gate);
  }
  if (g1) {
    conv_phase<64, 128, 32, 32, true, 4, true>(bid, tid, wc2, cnt, 1, 2, iws + I_L1, BS_L1,
                                               iws + I_P1, BS_P1, sump + 0, s_acc, s_plb, s_spb,
                                               s_big, s_list, &s_n, &s_base, &s_uc, s_cnt);
    gbar(bar, tid);
    g2 = layer_any(cnt, 2, tid, &s_gate);
  }
  if (g2) {
    conv_phase<128, 256, 16, 16, true, 8, true>(bid, tid, wc3, cnt, 2, 3, iws + I_P1, BS_P1,
                                                iws + I_P2, BS_P2, sump + 8, s_acc, s_plb, s_spb,
                                                s_big, s_list, &s_n, &s_base, &s_uc, s_cnt);
    gbar(bar, tid);
    g3 = layer_any(cnt, 3, tid, &s_gate);
  }
  if (g3) {
    conv_phase<256, 512, 8, 8, false, 16, false>(bid, tid, wc4, cnt, 3, 4, iws + I_P2, BS_P2,
                                                 iws + I_L4, BS_L4, nullptr, s_acc, s_plb, s_spb,
                                                 s_big, s_list, &s_n, &s_base, &s_uc, s_cnt);
    gbar(bar, tid);
    g4 = layer_any(cnt, 4, tid, &s_gate);
  }
  if (g4) {
    conv_phase<512, 256, 8, 8, false, 8, false>(bid, tid, wc5, cnt, 4, 5, iws + I_L4, BS_L4,
                                                iws + I_L5, BS_L5, nullptr, s_acc, s_plb, s_spb,
                                                s_big, s_list, &s_n, &s_base, &s_uc, s_cnt);
    gbar(bar, tid);
    g5 = layer_any(cnt, 5, tid, &s_gate);
  }
  if (g5) {
    if (bid < B * 1024 / 256)
      fc_phase<16384, 1024>(bid, tid, wf1, cnt, 5, 6, iws + I_L5, BS_L5, iws + I_F1, BS_F1,
                            s_list, &s_n, &s_base, s_cnt);
    gbar(bar, tid);
    g6 = layer_any(cnt, 6, tid, &s_gate);
  }
  if (g6) {
    if (bid < B * 512 / 256)
      fc_phase<1024, 512>(bid, tid, wf2, cnt, 6, 7, iws + I_F1, BS_F1, iws + I_F2, BS_F2,
                          s_list, &s_n, &s_base, s_cnt);
    gbar(bar, tid);
  }
  if (bid == 0)
    fc3_phase(tid, wf3, cnt, 7, iws + I_F2, BS_F2, sump, out, &s_c3);
}

extern "C" void kernel_launch(void* const* d_in, const int* in_sizes, int n_in, void* d_out,
                              int out_size, void* d_ws, size_t ws_size, hipStream_t stream) {
  const float* input = (const float*)d_in[0];
  const float* wc1 = (const float*)d_in[1];
  const float* wc2 = (const float*)d_in[2];
  const float* wc3 = (const float*)d_in[3];
  const float* wc4 = (const float*)d_in[4];
  const float* wc5 = (const float*)d_in[5];
  const float* wf1 = (const float*)d_in[6];
  const float* wf2 = (const float*)d_in[7];
  const float* wf3 = (const float*)d_in[8];
  float* out = (float*)d_out;
  int* iws = (int*)d_ws;
  if (ws_size < WS_NEED) return;  // ~43 MB needed

  k_encode<<<B, 512, 0, stream>>>(input, iws);
  k_tail<<<TAIL_NB, 256, 0, stream>>>(wc1, wc2, wc3, wc4, wc5, wf1, wf2, wf3, out, iws);
}

// Round 16
// 67.604 us; speedup vs baseline: 1.9779x; 1.9779x over previous
//
#include <hip/hip_runtime.h>
#include <cstddef>

#define B 8
constexpr int TAIL_NB = 256;  // tail kernel grid (<= 256 CUs: co-resident, gbar-safe)

constexpr float DM = 0.95122942450071400910f; // exp(-1/20) in f32
constexpr float DS = 0.81873075307798185867f; // exp(-1/5) in f32

// bucket strides (elements per (t,b) bucket) = neurons per batch
constexpr int BS_L0 = 3 * 32 * 32;    // 3072
constexpr int BS_L1 = 64 * 32 * 32;   // 65536
constexpr int BS_P1 = 128 * 16 * 16;  // 32768
constexpr int BS_P2 = 256 * 8 * 8;    // 16384
constexpr int BS_L4 = 512 * 8 * 8;    // 32768
constexpr int BS_L5 = 256 * 8 * 8;    // 16384
constexpr int BS_F1 = 1024;
constexpr int BS_F2 = 512;

// ---- int workspace layout ----
constexpr size_t I_L0 = 0;
constexpr size_t I_L1 = I_L0 + 8 * (size_t)B * BS_L0;
constexpr size_t I_P1 = I_L1 + 8 * (size_t)B * BS_L1;
constexpr size_t I_P2 = I_P1 + 8 * (size_t)B * BS_P1;
constexpr size_t I_L4 = I_P2 + 8 * (size_t)B * BS_P2;
constexpr size_t I_L5 = I_L4 + 8 * (size_t)B * BS_L4;
constexpr size_t I_F1 = I_L5 + 8 * (size_t)B * BS_L5;
constexpr size_t I_F2 = I_F1 + 8 * (size_t)B * BS_F1;
constexpr size_t I_CNT = I_F2 + 8 * (size_t)B * BS_F2;  // 512 counters: [(t*8+ci)*8+b]
constexpr size_t I_SUMP = I_CNT + 512;                  // 16 floats: unpooled-count partials
constexpr size_t I_BAR = I_SUMP + 16;                   // 2 barrier words
constexpr size_t INT_TOTAL = I_BAR + 2;
constexpr size_t WS_NEED = INT_TOTAL * sizeof(int);  // ~43 MB

constexpr int ilog2(int n) { int l = 0; while (n > 1) { n >>= 1; ++l; } return l; }

__device__ __forceinline__ int ldcnt(const int* p) {
  return __hip_atomic_load(p, __ATOMIC_RELAXED, __HIP_MEMORY_SCOPE_AGENT);
}

__device__ __forceinline__ void block_stage(bool sp, int idx, int* s_list, int* s_n) {
  unsigned long long bal = __ballot(sp);
  if (bal == 0ull) return;
  int lane = threadIdx.x & 63;
  int leader = (int)__ffsll((unsigned long long)bal) - 1;
  int base = 0;
  if (lane == leader) base = atomicAdd(s_n, __popcll(bal));
  base = __shfl(base, leader);
  if (sp) s_list[base + __popcll(bal & ((1ull << lane) - 1ull))] = idx;
}

__device__ __forceinline__ void wave_append(bool sp, int idx, int* cnt, int* list) {
  unsigned long long bal = __ballot(sp);
  if (bal == 0ull) return;
  int lane = threadIdx.x & 63;
  int leader = (int)__ffsll((unsigned long long)bal) - 1;
  int base = 0;
  if (lane == leader) base = atomicAdd(cnt, __popcll(bal));
  base = __shfl(base, leader);
  if (sp) list[base + __popcll(bal & ((1ull << lane) - 1ull))] = idx;
}

// block-uniform layer gate (input counters are stable when this is called)
__device__ __forceinline__ bool layer_any(const int* cnt, int ci, int tid, int* s_gate) {
  __syncthreads();
  if (tid == 0) *s_gate = 0;
  __syncthreads();
  if (tid < 64) {
    int t = tid >> 3, b = tid & 7;
    if (ldcnt(cnt + (t * 8 + ci) * 8 + b) > 0) *s_gate = 1;
  }
  __syncthreads();
  return *s_gate != 0;
}

// generation barrier across TAIL_NB blocks (taken only on active path)
__device__ __forceinline__ void gbar(int* bar, int tid) {
  __threadfence();
  __syncthreads();
  if (tid == 0) {
    int g = __hip_atomic_load(bar + 1, __ATOMIC_RELAXED, __HIP_MEMORY_SCOPE_AGENT);
    int a = __hip_atomic_fetch_add(bar, 1, __ATOMIC_ACQ_REL, __HIP_MEMORY_SCOPE_AGENT);
    if (a == TAIL_NB - 1) {
      __hip_atomic_store(bar, 0, __ATOMIC_RELAXED, __HIP_MEMORY_SCOPE_AGENT);
      __hip_atomic_store(bar + 1, g + 1, __ATOMIC_RELEASE, __HIP_MEMORY_SCOPE_AGENT);
    } else {
      while (__hip_atomic_load(bar + 1, __ATOMIC_ACQUIRE, __HIP_MEMORY_SCOPE_AGENT) == g)
        __builtin_amdgcn_s_sleep(1);
    }
  }
  __syncthreads();
  __threadfence();
}

// encode + init, 8 blocks (one per batch) x 512 threads, TWO barriers total:
// phase1 all-step ballots -> barrier -> phase2 (8 waves scan one step each) ->
// barrier -> phase3 direct list stores. Also zeroes counters/sump/bar.
__global__ __launch_bounds__(512) void k_encode(const float* __restrict__ in,
                                                int* __restrict__ iws) {
  const int tid = threadIdx.x;
  const int b = blockIdx.x;
  int* cnt = iws + I_CNT;
  if (tid < 56) {  // zero cnt[(t,ci>=1,b)]
    int t = tid / 7, ci = 1 + tid % 7;
    cnt[(t * 8 + ci) * 8 + b] = 0;
  }
  if (b == 0 && tid >= 64 && tid < 82) iws[I_SUMP + (tid - 64)] = 0;  // sump + bar
  __shared__ unsigned long long s_bal[8 * 48];
  __shared__ int s_off[8 * 48];
  const int lane = tid & 63, w = tid >> 6;
  float x[6], u[6];
#pragma unroll
  for (int k = 0; k < 6; ++k) {
    x[k] = in[b * BS_L0 + tid + k * 512] * 0.2f;
    u[k] = 0.0f;
  }
  unsigned long long spmall = 0ull;  // bit t*6+k
#pragma clang loop unroll(disable)
  for (int t = 0; t < 8; ++t) {
#pragma unroll
    for (int k = 0; k < 6; ++k) {
      u[k] = DM * u[k] + x[k];
      bool sp = (u[k] - 1.0f > 0.0f);
      if (sp) { u[k] = 0.0f; spmall |= 1ull << (t * 6 + k); }
      unsigned long long bal = __ballot(sp);
      if (lane == 0) s_bal[t * 48 + k * 8 + w] = bal;
    }
  }
  __syncthreads();
  // wave w scans step t=w's 48 ballot popcounts (8 waves in parallel)
  if (lane < 48) {
    const int t = w;
    int v = __popcll(s_bal[t * 48 + lane]);
    int incl = v;
#pragma unroll
    for (int d = 1; d < 64; d <<= 1) {
      int o = __shfl_up(incl, d);
      if (lane >= d) incl += o;
    }
    s_off[t * 48 + lane] = incl - v;
    if (lane == 47) cnt[(t * 8 + 0) * 8 + b] = incl;  // layer-0 count (sole writer)
  }
  __syncthreads();
#pragma clang loop unroll(disable)
  for (int t = 0; t < 8; ++t) {
    int* list = iws + I_L0 + ((size_t)t * B + b) * BS_L0;
#pragma unroll
    for (int k = 0; k < 6; ++k) {
      if (spmall & (1ull << (t * 6 + k))) {
        int word = k * 8 + w;
        int rank = __popcll(s_bal[t * 48 + word] & ((1ull << lane) - 1ull));
        list[s_off[t * 48 + word] + rank] = tid + k * 512;
      }
    }
  }
}

// conv1 single-pass: 512 blocks (one per (b,oc) plane) x 1024 threads, TWO barriers.
// All 8 steps scattered into an 8-plane LDS accumulator (no inter-step barriers;
// independent atomics), then one 8-step register recurrence per pixel.
// Dead steps have cv=0 which is exactly 0-preserving, so no gating is needed.
__global__ __launch_bounds__(1024) void k_conv1(const float* __restrict__ w,
                                                int* __restrict__ iws) {
  const int tid = threadIdx.x;
  const int plane = blockIdx.x;
  const int b = plane >> 6;
  const int oc = plane & 63;
  int* cnt = iws + I_CNT;
  __shared__ float s_acc[8 * 1024];  // [t][pixel]
  __shared__ float s_w[75];
  __shared__ int s_cnt[8];
  if (tid < 8) s_cnt[tid] = ldcnt(cnt + (tid * 8 + 0) * 8 + b);
  if (tid >= 64 && tid < 139) s_w[tid - 64] = w[oc * 75 + (tid - 64)];
#pragma unroll
  for (int t = 0; t < 8; ++t) s_acc[t * 1024 + tid] = 0.0f;
  __syncthreads();
  // scatter all steps (no barriers between: different t-planes / independent atomics)
#pragma clang loop unroll(disable)
  for (int t = 0; t < 8; ++t) {
    const int S = s_cnt[t];
    if (S == 0) continue;
    const int* glist = iws + I_L0 + ((size_t)t * B + b) * BS_L0;
    const int total = S << 5;  // flattened (spike, patch-elem)
#pragma clang loop unroll(disable)
    for (int i = tid; i < total; i += 1024) {
      int k = i & 31;
      if (k < 25) {
        int loc = glist[i >> 5];  // 32 lanes share one entry: broadcast load
        int c = loc >> 10;
        int p = loc & 1023;
        int ki = (k * 205) >> 10;  // k/5 exact for k<25
        int oy = (p >> 5) + 2 - ki;
        int ox = (p & 31) + 2 - (k - ki * 5);
        if ((unsigned)oy < 32u && (unsigned)ox < 32u)
          atomicAdd(&s_acc[t * 1024 + (oy << 5) + ox], s_w[c * 25 + k]);
      }
    }
  }
  __syncthreads();
  // 8-step recurrence, 1 pixel/thread, all in registers
  float um = 0.0f, us = 0.0f, sav = 1.0f;
#pragma clang loop unroll(disable)
  for (int t = 0; t < 8; ++t) {
    float cv = s_acc[t * 1024 + tid];
    float m = DM * um + cv;
    float s2 = DS * us + cv;
    um = m;
    us = s2;
    float uu = sav * (m - s2);
    bool sp = (uu - 1.0f > 0.0f);
    if (sp) sav = 0.0f;
    wave_append(sp, (oc << 10) + tid, cnt + (t * 8 + 1) * 8 + b,
                iws + I_L1 + ((size_t)t * B + b) * BS_L1);
  }
}

// conv layer phase (tail)
template <int CIN, int COUT, int H, int W, bool POOL, int PPB, bool WLDS>
__device__ void conv_phase(int bid, int tid, const float* __restrict__ w, int* cnt, int in_ci,
                           int out_ci, const int* __restrict__ in_list0, int in_bs,
                           int* __restrict__ out_list0, int out_bs, float* sump_layer,
                           float* s_acc, float* s_plb, float* s_spb, float* s_w, int* s_list,
                           int* s_n, int* s_base, int* s_uc, int* s_cnt) {
  constexpr int HW = H * W;
  constexpr int HWlog = ilog2(HW);
  constexpr int Wlog = ilog2(W);
  constexpr int PPT = (HW + 255) / 256;
  int wcount = 0;
  const int b = (bid * PPB) >> ilog2(COUT);  // same batch for all planes in this block
  if (tid < 8) s_cnt[tid] = ldcnt(cnt + (tid * 8 + in_ci) * 8 + b);
  __syncthreads();
#pragma clang loop unroll(disable)
  for (int pl = 0; pl < PPB; ++pl) {
    const int plane = bid * PPB + pl;
    const int oc = plane & (COUT - 1);
    if constexpr (WLDS) {
#pragma clang loop unroll(disable)
      for (int j = tid; j < CIN * 25; j += 256) s_w[j] = w[(size_t)oc * CIN * 25 + j];
    }
    float um[PPT], us[PPT], sav[PPT], pe[PPT], plat[PPT];
#pragma unroll
    for (int k = 0; k < PPT; ++k) {
      um[k] = 0.0f; us[k] = 0.0f; sav[k] = 1.0f; pe[k] = 0.0f; plat[k] = 8.0f;
    }
    bool active = false;
#pragma clang loop unroll(disable)
    for (int t = 0; t < 8; ++t) {
      const int S = s_cnt[t];
      if (!active && S == 0) continue;
      active = true;
#pragma clang loop unroll(disable)
      for (int p = tid; p < HW; p += 256) s_acc[p] = 0.0f;
      if (tid == 0) *s_n = 0;
      __syncthreads();
      const int* list = in_list0 + ((size_t)t * B + b) * in_bs;
#pragma clang loop unroll(disable)
      for (int s = tid; s < S; s += 256) {
        int loc = list[s];
        int c = loc >> HWlog;
        int p = loc & (HW - 1);
        int y = p >> Wlog, x = p & (W - 1);
        const float* wp = WLDS ? (const float*)s_w + c * 25 : w + ((size_t)oc * CIN + c) * 25;
#pragma clang loop unroll(disable)
        for (int ki = 0; ki < 5; ++ki) {
          int oy = y + 2 - ki;
          if ((unsigned)oy < (unsigned)H) {
#pragma clang loop unroll(disable)
            for (int kj = 0; kj < 5; ++kj) {
              int ox = x + 2 - kj;
              if ((unsigned)ox < (unsigned)W) atomicAdd(&s_acc[oy * W + ox], wp[ki * 5 + kj]);
            }
          }
        }
      }
      __syncthreads();
#pragma unroll
      for (int k = 0; k < PPT; ++k) {
        int p = tid + k * 256;
        bool lane_ok = (p < HW);
        float cv = lane_ok ? s_acc[p] : 0.0f;
        float m = DM * um[k] + cv;
        float s2 = DS * us[k] + cv;
        um[k] = m;
        us[k] = s2;
        float uu = sav[k] * (m - s2);
        bool sp = lane_ok && (uu - 1.0f > 0.0f);
        if (sp) sav[k] = 0.0f;
        if constexpr (POOL) {
          unsigned long long bal = __ballot(sp);
          if ((tid & 63) == 0) wcount += (int)__popcll(bal);
          if (lane_ok) {
            float act = (m != 0.0f) ? 1.0f : 0.0f;
            float pen = pe[k] + (((pe[k] + act) != 0.0f) ? 1.0f : 0.0f);
            pe[k] = pen;
            if (sp) plat[k] += pen - 7.0f;
            s_plb[p] = plat[k];
            s_spb[p] = sp ? 1.0f : 0.0f;
          }
        } else {
          block_stage(sp, (oc << HWlog) + p, s_list, s_n);
        }
      }
      __syncthreads();
      if constexpr (POOL) {
        constexpr int HP = H / 2, WP = W / 2;
#pragma clang loop unroll(disable)
        for (int q = tid; q < HP * WP; q += 256) {
          int py = q / WP, px = q - py * WP;
          int base = (2 * py) * W + 2 * px;
          float l0 = s_plb[base], l1 = s_plb[base + 1], l2 = s_plb[base + W],
                l3 = s_plb[base + W + 1];
          int off = 0;
          float lm = l0;
          if (l1 < lm) { lm = l1; off = 1; }
          if (l2 < lm) { lm = l2; off = W; }
          if (l3 < lm) { lm = l3; off = W + 1; }
          bool psp = (s_spb[base + off] != 0.0f);
          block_stage(psp, oc * (HP * WP) + q, s_list, s_n);
        }
        __syncthreads();
      }
      if (tid == 0 && *s_n > 0) *s_base = atomicAdd(cnt + (t * 8 + out_ci) * 8 + b, *s_n);
      __syncthreads();
      int* out_list = out_list0 + ((size_t)t * B + b) * out_bs;
      int n = *s_n;
#pragma clang loop unroll(disable)
      for (int j = tid; j < n; j += 256) out_list[*s_base + j] = s_list[j];
      __syncthreads();
    }
  }
  if constexpr (POOL) {
    if (tid == 0) *s_uc = 0;
    __syncthreads();
    if ((tid & 63) == 0 && wcount) atomicAdd(s_uc, wcount);
    __syncthreads();
    if (tid == 0 && *s_uc) atomicAdd(sump_layer + b, (float)*s_uc);
  }
}

// fc layer phase (tail)
template <int IN, int OUT>
__device__ void fc_phase(int bid, int tid, const float* __restrict__ w, int* cnt, int in_ci,
                         int out_ci, const int* __restrict__ in_list0, int in_bs,
                         int* __restrict__ out_list0, int out_bs, int* s_list, int* s_n,
                         int* s_base, int* s_cnt) {
  const int q = bid * 256 + tid;
  const int b = q >> ilog2(OUT);
  const int o = q & (OUT - 1);
  if (tid < 8) s_cnt[tid] = ldcnt(cnt + (tid * 8 + in_ci) * 8 + b);
  __syncthreads();
  float um = 0.0f, us = 0.0f, sav = 1.0f;
  bool active = false;
#pragma clang loop unroll(disable)
  for (int t = 0; t < 8; ++t) {
    const int S = s_cnt[t];
    if (!active && S == 0) continue;
    active = true;
    if (tid == 0) *s_n = 0;
    __syncthreads();
    const int* list = in_list0 + ((size_t)t * B + b) * in_bs;
    float acc = 0.0f;
#pragma clang loop unroll(disable)
    for (int s = 0; s < S; ++s) acc += w[(size_t)o * IN + list[s]];
    float m = DM * um + acc;
    float s2 = DS * us + acc;
    um = m;
    us = s2;
    float uu = sav * (m - s2);
    bool sp = (uu - 1.0f > 0.0f);
    if (sp) sav = 0.0f;
    block_stage(sp, o, s_list, s_n);
    __syncthreads();
    if (tid == 0 && *s_n > 0) *s_base = atomicAdd(cnt + (t * 8 + out_ci) * 8 + b, *s_n);
    __syncthreads();
    int* out_list = out_list0 + ((size_t)t * B + b) * out_bs;
    int n = *s_n;
#pragma clang loop unroll(disable)
    for (int j = tid; j < n; j += 256) out_list[*s_base + j] = s_list[j];
    __syncthreads();
  }
}

// final FC (512->10) + te/out_t/out_u epilogue + sum_sp reduction (block 0)
__device__ void fc3_phase(int tid, const float* __restrict__ w, const int* cnt, int in_ci,
                          const int* __restrict__ in_list0, int in_bs,
                          const float* __restrict__ sump, float* __restrict__ out, int* s_c3) {
  if (tid == 0) *s_c3 = 0;
  __syncthreads();
  const bool lane_ok = (tid < 80);
  const int b = lane_ok ? tid / 10 : 0;
  const int o = lane_ok ? tid - b * 10 : 0;
  float um = 0.0f, us = 0.0f, sav = 1.0f, te = 0.0f, ot = 8.0f, ou = 0.0f;
  bool active = false;
#pragma clang loop unroll(disable)
  for (int t = 0; t < 8; ++t) {
    const int S = lane_ok ? ldcnt(cnt + (t * 8 + in_ci) * 8 + b) : 0;
    if (!active && !__any(S > 0)) continue;
    active = true;
    const int* list = in_list0 + ((size_t)t * B + b) * in_bs;
    float acc = 0.0f;
#pragma clang loop unroll(disable)
    for (int s = 0; s < S; ++s) acc += w[o * 512 + list[s]];
    float m = DM * um + acc;
    float s2 = DS * us + acc;
    um = m;
    us = s2;
    float uu = sav * (m - s2);
    bool sp = lane_ok && (uu - 1.0f > 0.0f);
    if (sp) sav = 0.0f;
    float act = (uu != 0.0f) ? 1.0f : 0.0f;
    te = te + (((te + act) != 0.0f) ? 1.0f : 0.0f);
    if (sp) {
      ot += te - 8.0f;
      ou += uu;
    }
    unsigned long long bal = __ballot(sp);
    if ((tid & 63) == 0 && bal) atomicAdd(s_c3, (int)__popcll(bal));
  }
  if (tid < 80) {
    out[tid] = ot;
    out[80 + tid] = ou;
  }
  __syncthreads();
  if (tid < 8) {
    float s = 0.0f;
    if (tid == 2 || tid == 3) {
      const float* sp = sump + (tid - 2) * 8;
      for (int b2 = 0; b2 < 8; ++b2) s += sp[b2];
    } else {
      for (int t = 0; t < 8; ++t)
        for (int b2 = 0; b2 < 8; ++b2) s += (float)cnt[(t * 8 + tid) * 8 + b2];
    }
    out[160 + tid] = s;
  }
  if (tid == 0) out[168] = (float)*s_c3;
}

// ONE tail dispatch: conv2..fc2 gated phases + fc3 epilogue. Barriers only on active path.
__global__ __launch_bounds__(256) void k_tail(const float* __restrict__ wc2,
                                              const float* __restrict__ wc3,
                                              const float* __restrict__ wc4,
                                              const float* __restrict__ wc5,
                                              const float* __restrict__ wf1,
                                              const float* __restrict__ wf2,
                                              const float* __restrict__ wf3,
                                              float* __restrict__ out, int* __restrict__ iws) {
  __shared__ float s_w[3200];
  __shared__ float s_acc[1024];
  __shared__ float s_plb[1024];
  __shared__ float s_spb[1024];
  __shared__ int s_list[1024];
  __shared__ int s_n, s_base, s_uc, s_gate, s_c3, s_cnt[8];
  const int tid = threadIdx.x;
  const int bid = blockIdx.x;
  int* cnt = iws + I_CNT;
  float* sump = (float*)(iws + I_SUMP);
  int* bar = iws + I_BAR;

  if (layer_any(cnt, 1, tid, &s_gate)) {
    conv_phase<64, 128, 32, 32, true, 4, true>(bid, tid, wc2, cnt, 1, 2, iws + I_L1, BS_L1,
                                               iws + I_P1, BS_P1, sump + 0, s_acc, s_plb, s_spb,
                                               s_w, s_list, &s_n, &s_base, &s_uc, s_cnt);
    gbar(bar, tid);
  }
  if (layer_any(cnt, 2, tid, &s_gate)) {
    conv_phase<128, 256, 16, 16, true, 8, true>(bid, tid, wc3, cnt, 2, 3, iws + I_P1, BS_P1,
                                                iws + I_P2, BS_P2, sump + 8, s_acc, s_plb, s_spb,
                                                s_w, s_list, &s_n, &s_base, &s_uc, s_cnt);
    gbar(bar, tid);
  }
  if (layer_any(cnt, 3, tid, &s_gate)) {
    conv_phase<256, 512, 8, 8, false, 16, false>(bid, tid, wc4, cnt, 3, 4, iws + I_P2, BS_P2,
                                                 iws + I_L4, BS_L4, nullptr, s_acc, s_plb, s_spb,
                                                 s_w, s_list, &s_n, &s_base, &s_uc, s_cnt);
    gbar(bar, tid);
  }
  if (layer_any(cnt, 4, tid, &s_gate)) {
    conv_phase<512, 256, 8, 8, false, 8, false>(bid, tid, wc5, cnt, 4, 5, iws + I_L4, BS_L4,
                                                iws + I_L5, BS_L5, nullptr, s_acc, s_plb, s_spb,
                                                s_w, s_list, &s_n, &s_base, &s_uc, s_cnt);
    gbar(bar, tid);
  }
  if (layer_any(cnt, 5, tid, &s_gate)) {
    if (bid < B * 1024 / 256)
      fc_phase<16384, 1024>(bid, tid, wf1, cnt, 5, 6, iws + I_L5, BS_L5, iws + I_F1, BS_F1,
                            s_list, &s_n, &s_base, s_cnt);
    gbar(bar, tid);
  }
  if (layer_any(cnt, 6, tid, &s_gate)) {
    if (bid < B * 512 / 256)
      fc_phase<1024, 512>(bid, tid, wf2, cnt, 6, 7, iws + I_F1, BS_F1, iws + I_F2, BS_F2,
                          s_list, &s_n, &s_base, s_cnt);
    gbar(bar, tid);
  }
  if (bid == 0)
    fc3_phase(tid, wf3, cnt, 7, iws + I_F2, BS_F2, sump, out, &s_c3);
}

extern "C" void kernel_launch(void* const* d_in, const int* in_sizes, int n_in, void* d_out,
                              int out_size, void* d_ws, size_t ws_size, hipStream_t stream) {
  const float* input = (const float*)d_in[0];
  const float* wc1 = (const float*)d_in[1];
  const float* wc2 = (const float*)d_in[2];
  const float* wc3 = (const float*)d_in[3];
  const float* wc4 = (const float*)d_in[4];
  const float* wc5 = (const float*)d_in[5];
  const float* wf1 = (const float*)d_in[6];
  const float* wf2 = (const float*)d_in[7];
  const float* wf3 = (const float*)d_in[8];
  float* out = (float*)d_out;
  int* iws = (int*)d_ws;
  if (ws_size < WS_NEED) return;  // ~43 MB needed

  k_encode<<<B, 512, 0, stream>>>(input, iws);
  k_conv1<<<512, 1024, 0, stream>>>(wc1, iws);
  k_tail<<<TAIL_NB, 256, 0, stream>>>(wc2, wc3, wc4, wc5, wf1, wf2, wf3, out, iws);
}